// Round 5
// baseline (293.974 us; speedup 1.0000x reference)
//
#include <hip/hip_runtime.h>
#include <math.h>

#define T_TOK 2048
#define DM 1024
#define HQ 16
#define HD 64
#define NB 32
#define BS 64
#define S_SEL 16
#define NEGF (-1e30f)

typedef __attribute__((ext_vector_type(8))) short bf16x8;
typedef __attribute__((ext_vector_type(4))) float f32x4;
typedef unsigned short ush;

__device__ __forceinline__ ush f2bf(float x) {
  unsigned u = __float_as_uint(x);
  return (ush)((u + 0x7fffu + ((u >> 16) & 1u)) >> 16);
}
__device__ __forceinline__ float bf2f(ush h) {
  return __uint_as_float(((unsigned)h) << 16);
}

// ---- decompose weights + x into bf16 hi/lo planes (one launch, 6 segments) --
__global__ __launch_bounds__(256) void split_w6(
    const float* __restrict__ s0, const float* __restrict__ s1,
    const float* __restrict__ s2, const float* __restrict__ s3,
    const float* __restrict__ s4, const float* __restrict__ s5,
    ush* h0, ush* l0, ush* h1, ush* l1, ush* h2, ush* l2,
    ush* h3, ush* l3, ush* h4, ush* l4, ush* h5, ush* l5)
{
  const float* srcs[6] = {s0, s1, s2, s3, s4, s5};
  ush* hs[6] = {h0, h1, h2, h3, h4, h5};
  ush* ls[6] = {l0, l1, l2, l3, l4, l5};
  const int ns[6] = {1048576, 65536, 65536, 49152, 1048576, 2097152};
  int seg = blockIdx.y;
  int i = (blockIdx.x * 256 + threadIdx.x) * 4;
  if (i >= ns[seg]) return;
  float4 v = *(const float4*)(srcs[seg] + i);
  ushort4 hv, lv;
  hv.x = f2bf(v.x); lv.x = f2bf(v.x - bf2f(hv.x));
  hv.y = f2bf(v.y); lv.y = f2bf(v.y - bf2f(hv.y));
  hv.z = f2bf(v.z); lv.z = f2bf(v.z - bf2f(hv.z));
  hv.w = f2bf(v.w); lv.w = f2bf(v.w - bf2f(hv.w));
  *(ushort4*)(hs[seg] + i) = hv;
  *(ushort4*)(ls[seg] + i) = lv;
}

// ---- split-bf16 MFMA GEMM body: Y = A @ W^T, 64x64 tile, BK=32 --------------
// A pre-split hi/lo planes. 4 waves 2x2; wave tile 32x32; 12 MFMAs/iter.
// Outputs: optional f32 Yf, hi/lo planes Yh/Yl, transposed-hi YT[n][m].
__device__ __forceinline__ void gemm64_body(
    const ush* __restrict__ Ah_, const ush* __restrict__ Al_,
    const ush* __restrict__ Wh, const ush* __restrict__ Wl,
    float* Yf, ush* Yh, ush* Yl, ush* YT, int N, int K, int m0, int n0,
    ush Ash[64][40], ush Asl[64][40], ush Bsh[64][40], ush Bsl[64][40])
{
  const int tid = threadIdx.x;
  const int wave = tid >> 6, lane = tid & 63;
  const int quad = lane >> 4, c16 = lane & 15;
  const int wm = wave >> 1, wn = wave & 1;
  const int ar = tid >> 2, ac = (tid & 3) * 8;
  f32x4 acc[2][2] = {};
  for (int k0 = 0; k0 < K; k0 += 32) {
    __syncthreads();
    {
      *(bf16x8*)&Ash[ar][ac] = *(const bf16x8*)(Ah_ + (size_t)(m0 + ar) * K + k0 + ac);
      *(bf16x8*)&Asl[ar][ac] = *(const bf16x8*)(Al_ + (size_t)(m0 + ar) * K + k0 + ac);
      bf16x8 bh = {}, bl = {};
      if (n0 + ar < N) {
        bh = *(const bf16x8*)(Wh + (size_t)(n0 + ar) * K + k0 + ac);
        bl = *(const bf16x8*)(Wl + (size_t)(n0 + ar) * K + k0 + ac);
      }
      *(bf16x8*)&Bsh[ar][ac] = bh;
      *(bf16x8*)&Bsl[ar][ac] = bl;
    }
    __syncthreads();
    bf16x8 Ah[2], Al[2], Bh[2], Bl[2];
    #pragma unroll
    for (int mt = 0; mt < 2; ++mt) {
      Ah[mt] = *(const bf16x8*)&Ash[wm*32 + mt*16 + c16][quad*8];
      Al[mt] = *(const bf16x8*)&Asl[wm*32 + mt*16 + c16][quad*8];
    }
    #pragma unroll
    for (int nt = 0; nt < 2; ++nt) {
      Bh[nt] = *(const bf16x8*)&Bsh[wn*32 + nt*16 + c16][quad*8];
      Bl[nt] = *(const bf16x8*)&Bsl[wn*32 + nt*16 + c16][quad*8];
    }
    #pragma unroll
    for (int mt = 0; mt < 2; ++mt)
      #pragma unroll
      for (int nt = 0; nt < 2; ++nt) {
        acc[mt][nt] = __builtin_amdgcn_mfma_f32_16x16x32_bf16(Ah[mt], Bh[nt], acc[mt][nt], 0, 0, 0);
        acc[mt][nt] = __builtin_amdgcn_mfma_f32_16x16x32_bf16(Ah[mt], Bl[nt], acc[mt][nt], 0, 0, 0);
        acc[mt][nt] = __builtin_amdgcn_mfma_f32_16x16x32_bf16(Al[mt], Bh[nt], acc[mt][nt], 0, 0, 0);
      }
  }
  #pragma unroll
  for (int mt = 0; mt < 2; ++mt)
    #pragma unroll
    for (int nt = 0; nt < 2; ++nt) {
      int n = n0 + wn*32 + nt*16 + c16;
      if (n < N) {
        #pragma unroll
        for (int r = 0; r < 4; ++r) {
          int m = m0 + wm*32 + mt*16 + quad*4 + r;
          float vvv = acc[mt][nt][r];
          if (Yf) Yf[(size_t)m*N + n] = vvv;
          ush hb = f2bf(vvv);
          if (Yh) {
            Yh[(size_t)m*N + n] = hb;
            if (Yl) Yl[(size_t)m*N + n] = f2bf(vvv - bf2f(hb));
          }
          if (YT) YT[(size_t)n*T_TOK + m] = hb;
        }
      }
    }
}

__global__ __launch_bounds__(256) void gemm_split(
    const ush* __restrict__ Ah, const ush* __restrict__ Al,
    const ush* __restrict__ Wh, const ush* __restrict__ Wl,
    float* Yf, ush* Yh, ush* Yl, int N, int K)
{
  __shared__ ush Ash[64][40], Asl[64][40], Bsh[64][40], Bsl[64][40];
  gemm64_body(Ah, Al, Wh, Wl, Yf, Yh, Yl, nullptr, N, K,
              blockIdx.y*64, blockIdx.x*64, Ash, Asl, Bsh, Bsl);
}

// fused k/v/g projections: blockIdx.x = segment. v also writes transposed hi.
__global__ __launch_bounds__(256) void gemm_kvg(
    const ush* __restrict__ xh, const ush* __restrict__ xl,
    const ush* __restrict__ Wkh, const ush* __restrict__ Wkl,
    const ush* __restrict__ Wvh, const ush* __restrict__ Wvl,
    const ush* __restrict__ Wgh, const ush* __restrict__ Wgl,
    float* kbuf, ush* kb, float* vbuf, ush* vbT, float* gpj, int K)
{
  __shared__ ush Ash[64][40], Asl[64][40], Bsh[64][40], Bsl[64][40];
  const int seg = blockIdx.x;
  const ush *wh, *wl; float* yf; ush* yh = nullptr; ush* yt = nullptr; int N;
  if (seg == 0)      { wh = Wkh; wl = Wkl; yf = kbuf; yh = kb; N = 64; }
  else if (seg == 1) { wh = Wvh; wl = Wvl; yf = vbuf; yt = vbT; N = 64; }
  else               { wh = Wgh; wl = Wgl; yf = gpj;  N = 48; }
  gemm64_body(xh, xl, wh, wl, yf, yh, nullptr, yt, N, K, blockIdx.y*64, 0,
              Ash, Asl, Bsh, Bsl);
}

// ---- mean-pool k,v into centroids, emit split-bf16 (kc [c][d], vcT [d][c]) --
__global__ void pool_kv(const float* __restrict__ k, const float* __restrict__ v,
    ush* __restrict__ kch, ush* __restrict__ kcl,
    ush* __restrict__ vth, ush* __restrict__ vtl)
{
  int c = blockIdx.x, d = threadIdx.x;
  float sk = 0.f, sv = 0.f;
  for (int i = 0; i < BS; ++i) {
    sk += k[(size_t)(c*BS + i)*HD + d];
    sv += v[(size_t)(c*BS + i)*HD + d];
  }
  sk *= (1.f/BS); sv *= (1.f/BS);
  ush kh = f2bf(sk);
  kch[c*HD + d] = kh;
  kcl[c*HD + d] = f2bf(sk - bf2f(kh));
  ush vh = f2bf(sv);
  vth[d*NB + c] = vh;
  vtl[d*NB + c] = f2bf(sv - bf2f(vh));
}

// ---- compressed attention + top-k, MFMA, one wave per token (4 tokens/WG) ---
// o_cmp emitted as bf16 hi/lo planes (consumed by sel epilogue + out-GEMM).
__global__ __launch_bounds__(256) void cmp_attn_mfma(
    const ush* __restrict__ qh, const ush* __restrict__ ql,
    const ush* __restrict__ kch, const ush* __restrict__ kcl,
    const ush* __restrict__ vth, const ush* __restrict__ vtl,
    ush* __restrict__ och, ush* __restrict__ ocl, int* __restrict__ blkp)
{
  __shared__ float Pls[4][16][36];
  const int tid = threadIdx.x, w = tid >> 6, lane = tid & 63;
  const int quad = lane >> 4, c16 = lane & 15;
  const int t = blockIdx.x * 4 + w;

  const ush* qrh = qh + (size_t)t*DM + c16*HD + quad*8;
  const ush* qrl = ql + (size_t)t*DM + c16*HD + quad*8;
  bf16x8 qah0 = *(const bf16x8*)(qrh);
  bf16x8 qah1 = *(const bf16x8*)(qrh + 32);
  bf16x8 qal0 = *(const bf16x8*)(qrl);
  bf16x8 qal1 = *(const bf16x8*)(qrl + 32);

  f32x4 s[2];
  #pragma unroll
  for (int nh = 0; nh < 2; ++nh) {
    const int crow = nh*16 + c16;
    bf16x8 kh0 = *(const bf16x8*)(kch + crow*HD + quad*8);
    bf16x8 kh1 = *(const bf16x8*)(kch + crow*HD + 32 + quad*8);
    bf16x8 kl0 = *(const bf16x8*)(kcl + crow*HD + quad*8);
    bf16x8 kl1 = *(const bf16x8*)(kcl + crow*HD + 32 + quad*8);
    f32x4 acc = {0.f, 0.f, 0.f, 0.f};
    acc = __builtin_amdgcn_mfma_f32_16x16x32_bf16(qah0, kh0, acc, 0, 0, 0);
    acc = __builtin_amdgcn_mfma_f32_16x16x32_bf16(qah1, kh1, acc, 0, 0, 0);
    acc = __builtin_amdgcn_mfma_f32_16x16x32_bf16(qah0, kl0, acc, 0, 0, 0);
    acc = __builtin_amdgcn_mfma_f32_16x16x32_bf16(qah1, kl1, acc, 0, 0, 0);
    acc = __builtin_amdgcn_mfma_f32_16x16x32_bf16(qal0, kh0, acc, 0, 0, 0);
    acc = __builtin_amdgcn_mfma_f32_16x16x32_bf16(qal1, kh1, acc, 0, 0, 0);
    s[nh] = acc;
  }

  const int nvis = (t + 1) >> 6;
  const bool visA = (c16 < nvis), visB = (16 + c16 < nvis);
  float p[2][4];
  float iA = 0.f, iB = 0.f;
  #pragma unroll
  for (int r = 0; r < 4; ++r) {
    float sA = s[0][r] * 0.125f, sB = s[1][r] * 0.125f;
    float m = fmaxf(visA ? sA : -INFINITY, visB ? sB : -INFINITY);
    #pragma unroll
    for (int off = 1; off < 16; off <<= 1) m = fmaxf(m, __shfl_xor(m, off));
    float eA = visA ? __expf(sA - m) : 0.f;
    float eB = visB ? __expf(sB - m) : 0.f;
    float l = eA + eB;
    #pragma unroll
    for (int off = 1; off < 16; off <<= 1) l += __shfl_xor(l, off);
    float inv = (l > 0.f) ? 1.f / l : 0.f;
    p[0][r] = eA * inv; p[1][r] = eB * inv;
    iA += p[0][r]; iB += p[1][r];
  }
  iA += __shfl_xor(iA, 16); iA += __shfl_xor(iA, 32);
  iB += __shfl_xor(iB, 16); iB += __shfl_xor(iB, 32);

  #pragma unroll
  for (int nh = 0; nh < 2; ++nh)
    #pragma unroll
    for (int r = 0; r < 4; ++r)
      Pls[w][quad*4 + r][nh*16 + c16] = p[nh][r];

  {
    const int cur = t >> 6;
    float a;
    if (lane < 16) a = iA;
    else if (lane < 32) a = iB;
    else a = -INFINITY;
    if (lane < 32) {
      if (lane > cur) a = NEGF;
      if (lane == 0 || lane == cur) a = INFINITY;
    }
    for (int sidx = 0; sidx < S_SEL; ++sidx) {
      float bv = a; int bi = lane;
      #pragma unroll
      for (int off = 1; off < 64; off <<= 1) {
        float ov = __shfl_xor(bv, off); int oi = __shfl_xor(bi, off);
        if (ov > bv || (ov == bv && oi < bi)) { bv = ov; bi = oi; }
      }
      if (lane == 0) blkp[t*S_SEL + sidx] = bi;
      if (lane == bi) a = -INFINITY;
    }
  }
  __syncthreads();

  float4 pa = *(const float4*)&Pls[w][c16][quad*8];
  float4 pb = *(const float4*)&Pls[w][c16][quad*8 + 4];
  float pf[8] = {pa.x, pa.y, pa.z, pa.w, pb.x, pb.y, pb.z, pb.w};
  bf16x8 pah, pal;
  #pragma unroll
  for (int j = 0; j < 8; ++j) {
    ush hb = f2bf(pf[j]);
    pah[j] = (short)hb;
    pal[j] = (short)f2bf(pf[j] - bf2f(hb));
  }
  #pragma unroll
  for (int nb = 0; nb < 4; ++nb) {
    const int drow = nb*16 + c16;
    bf16x8 vh8 = *(const bf16x8*)(vth + drow*NB + quad*8);
    bf16x8 vl8 = *(const bf16x8*)(vtl + drow*NB + quad*8);
    f32x4 acc = {0.f, 0.f, 0.f, 0.f};
    acc = __builtin_amdgcn_mfma_f32_16x16x32_bf16(pah, vh8, acc, 0, 0, 0);
    acc = __builtin_amdgcn_mfma_f32_16x16x32_bf16(pah, vl8, acc, 0, 0, 0);
    acc = __builtin_amdgcn_mfma_f32_16x16x32_bf16(pal, vh8, acc, 0, 0, 0);
    #pragma unroll
    for (int r = 0; r < 4; ++r) {
      float val = acc[r];
      size_t idx = (size_t)t*DM + (quad*4 + r)*HD + nb*16 + c16;
      ush hb = f2bf(val);
      och[idx] = hb;
      ocl[idx] = f2bf(val - bf2f(hb));
    }
  }
}

// ---- selected attention: barrier-free MFMA; K and V^T direct from global ----
// Q K^T: B-frag = kb[(blk*64+w*16+c)*64 + quad*8] (16B/lane, contiguous).
// P V  : A-frag from Pb (LDS), B-frag = vbT[(16w+c)*2048 + blk*64+...] (16B).
#define PBW 1032
__global__ __launch_bounds__(256) void sel_attn_mfma(
    const ush* __restrict__ qbh, const ush* __restrict__ kb,
    const ush* __restrict__ vbT, const float* __restrict__ gp,
    const int* __restrict__ blkp,
    ush* __restrict__ och, ush* __restrict__ ocl)
{
  const int t = blockIdx.x, tid = threadIdx.x;
  const int w = tid >> 6, lane = tid & 63;
  const int quad = lane >> 4, c = lane & 15;

  __shared__ ush Pb[16][PBW];                    // 33 KB
  __shared__ int   blk_s[16];
  __shared__ float redm[4][16], redl[4][16];
  __shared__ float gm[16], invl[16], gc[16], gs[16];

  if (tid < 16) {
    blk_s[tid] = blkp[t*S_SEL + tid];
    float a = gp[(size_t)t*48 + tid*3 + 0];
    float b = gp[(size_t)t*48 + tid*3 + 1];
    gc[tid] = 1.f/(1.f + __expf(-a));
    gs[tid] = 1.f/(1.f + __expf(-b));
  }
  const ush* qrow = qbh + (size_t)t*DM + c*HD + quad*8;
  bf16x8 qa0 = *(const bf16x8*)(qrow);
  bf16x8 qa1 = *(const bf16x8*)(qrow + 32);
  __syncthreads();

  // ---- phase 1: S = Q K^T, no LDS staging, no barriers ----------------------
  f32x4 S[16];
  #pragma unroll 4
  for (int b = 0; b < 16; ++b) {
    const int blk = blk_s[b];
    const ush* kp = kb + ((size_t)blk*BS + w*16 + c) * HD + quad*8;
    bf16x8 b0 = *(const bf16x8*)(kp);
    bf16x8 b1 = *(const bf16x8*)(kp + 32);
    f32x4 acc = {0.f, 0.f, 0.f, 0.f};
    acc = __builtin_amdgcn_mfma_f32_16x16x32_bf16(qa0, b0, acc, 0, 0, 0);
    acc = __builtin_amdgcn_mfma_f32_16x16x32_bf16(qa1, b1, acc, 0, 0, 0);
    const int tok = blk*BS + w*16 + c;
    const bool ok = (tok <= t);
    #pragma unroll
    for (int r = 0; r < 4; ++r) S[b][r] = ok ? acc[r]*0.125f : NEGF;
  }

  // ---- softmax (registers + shuffles + small LDS cross-wave reduce) ---------
  f32x4 mx = S[0];
  #pragma unroll
  for (int b = 1; b < 16; ++b)
    #pragma unroll
    for (int r = 0; r < 4; ++r) mx[r] = fmaxf(mx[r], S[b][r]);
  #pragma unroll
  for (int off = 1; off < 16; off <<= 1)
    #pragma unroll
    for (int r = 0; r < 4; ++r) mx[r] = fmaxf(mx[r], __shfl_xor(mx[r], off));
  if (c == 0) {
    #pragma unroll
    for (int r = 0; r < 4; ++r) redm[w][quad*4 + r] = mx[r];
  }
  __syncthreads();
  if (tid < 16)
    gm[tid] = fmaxf(fmaxf(redm[0][tid], redm[1][tid]),
                    fmaxf(redm[2][tid], redm[3][tid]));
  __syncthreads();
  f32x4 M;
  #pragma unroll
  for (int r = 0; r < 4; ++r) M[r] = gm[quad*4 + r];

  f32x4 lsum = {0.f, 0.f, 0.f, 0.f};
  #pragma unroll
  for (int b = 0; b < 16; ++b) {
    #pragma unroll
    for (int r = 0; r < 4; ++r) {
      ush pbv = f2bf(__expf(S[b][r] - M[r]));
      Pb[quad*4 + r][b*64 + w*16 + c] = pbv;
      lsum[r] += bf2f(pbv);
    }
  }
  #pragma unroll
  for (int off = 1; off < 16; off <<= 1)
    #pragma unroll
    for (int r = 0; r < 4; ++r) lsum[r] += __shfl_xor(lsum[r], off);
  if (c == 0) {
    #pragma unroll
    for (int r = 0; r < 4; ++r) redl[w][quad*4 + r] = lsum[r];
  }
  __syncthreads();
  if (tid < 16)
    invl[tid] = 1.f / (redl[0][tid] + redl[1][tid] + redl[2][tid] + redl[3][tid]);
  __syncthreads();                               // Pb + invl ready

  // ---- phase 2: O = P V, A from LDS, B direct from global vbT ---------------
  f32x4 accO = {0.f, 0.f, 0.f, 0.f};
  const int drow = 16*w + c;                     // this lane's d
  const ush* vrow = vbT + (size_t)drow * T_TOK;
  #pragma unroll 2
  for (int ci = 0; ci < 8; ++ci) {
    #pragma unroll
    for (int kk = 0; kk < 4; ++kk) {
      const int blk = blk_s[2*ci + (kk >> 1)];
      bf16x8 B = *(const bf16x8*)(vrow + blk*BS + (kk & 1)*32 + quad*8);
      bf16x8 A = *(const bf16x8*)&Pb[c][128*ci + 32*kk + quad*8];
      accO = __builtin_amdgcn_mfma_f32_16x16x32_bf16(A, B, accO, 0, 0, 0);
    }
  }

  // ---- epilogue: gate + combine with o_cmp (hi/lo planes, in place) ---------
  #pragma unroll
  for (int r = 0; r < 4; ++r) {
    const int h = quad*4 + r;
    size_t idx = (size_t)t*DM + h*HD + drow;
    float oc = bf2f(och[idx]) + bf2f(ocl[idx]);
    float val = accO[r] * invl[h] * gs[h] + oc * gc[h];
    ush hb = f2bf(val);
    och[idx] = hb;
    ocl[idx] = f2bf(val - bf2f(hb));
  }
}

extern "C" void kernel_launch(void* const* d_in, const int* in_sizes, int n_in,
                              void* d_out, int out_size, void* d_ws, size_t ws_size,
                              hipStream_t stream)
{
  const float* x  = (const float*)d_in[0];
  const float* Wq = (const float*)d_in[1];
  const float* Wk = (const float*)d_in[2];
  const float* Wv = (const float*)d_in[3];
  const float* Wg = (const float*)d_in[4];
  const float* Wo = (const float*)d_in[5];
  float* out = (float*)d_out;

  float* ws   = (float*)d_ws;
  float* kbuf = ws;                                // 2048*64 f32
  float* vbuf = kbuf + (size_t)T_TOK*HD;
  float* gpj  = vbuf + (size_t)T_TOK*HD;           // 2048*48 f32
  int*   blkp = (int*)(gpj + (size_t)T_TOK*48);    // 2048*16
  ush* xh  = (ush*)(blkp + T_TOK*S_SEL);           // 2048*1024 (reused as och)
  ush* xl  = xh + (size_t)T_TOK*DM;                // (reused as ocl)
  ush* qbh = xl + (size_t)T_TOK*DM;
  ush* qbl = qbh + (size_t)T_TOK*DM;
  ush* kb  = qbl + (size_t)T_TOK*DM;               // 2048*64
  ush* vbT = kb  + (size_t)T_TOK*HD;               // 64*2048 (transposed)
  ush* kch = vbT + (size_t)T_TOK*HD;
  ush* kcl = kch + NB*HD;
  ush* vth = kcl + NB*HD;
  ush* vtl = vth + NB*HD;
  ush* Wqh = vtl + NB*HD;
  ush* Wql = Wqh + 1048576;
  ush* Wkh = Wql + 1048576;
  ush* Wkl = Wkh + 65536;
  ush* Wvh = Wkl + 65536;
  ush* Wvl = Wvh + 65536;
  ush* Wgh = Wvl + 65536;
  ush* Wgl = Wgh + 49152;
  ush* Woh = Wgl + 49152;
  ush* Wol = Woh + 1048576;
  ush* och = xh;   // overlay: x planes dead after the projection GEMMs
  ush* ocl = xl;

  split_w6<<<dim3(2048, 6), 256, 0, stream>>>(Wq, Wk, Wv, Wg, Wo, x,
      Wqh, Wql, Wkh, Wkl, Wvh, Wvl, Wgh, Wgl, Woh, Wol, xh, xl);
  gemm_split<<<dim3(16, 32), 256, 0, stream>>>(xh, xl, Wqh, Wql,
      nullptr, qbh, qbl, DM, DM);
  gemm_kvg<<<dim3(3, 32), 256, 0, stream>>>(xh, xl, Wkh, Wkl, Wvh, Wvl,
      Wgh, Wgl, kbuf, kb, vbuf, vbT, gpj, DM);
  pool_kv<<<NB, HD, 0, stream>>>(kbuf, vbuf, kch, kcl, vth, vtl);
  cmp_attn_mfma<<<T_TOK/4, 256, 0, stream>>>(qbh, qbl, kch, kcl, vth, vtl,
      och, ocl, blkp);
  sel_attn_mfma<<<T_TOK, 256, 0, stream>>>(qbh, kb, vbT, gpj, blkp, och, ocl);
  gemm_split<<<dim3(16, 32), 256, 0, stream>>>(och, ocl, Woh, Wol,
      out, nullptr, nullptr, DM, DM);
}

// Round 6
// 249.950 us; speedup vs baseline: 1.1761x; 1.1761x over previous
//
#include <hip/hip_runtime.h>
#include <math.h>

#define T_TOK 2048
#define DM 1024
#define HQ 16
#define HD 64
#define NB 32
#define BS 64
#define S_SEL 16
#define NEGF (-1e30f)

typedef __attribute__((ext_vector_type(8))) short bf16x8;
typedef __attribute__((ext_vector_type(4))) float f32x4;
typedef unsigned short ush;

__device__ __forceinline__ ush f2bf(float x) {
  unsigned u = __float_as_uint(x);
  return (ush)((u + 0x7fffu + ((u >> 16) & 1u)) >> 16);
}
__device__ __forceinline__ float bf2f(ush h) {
  return __uint_as_float(((unsigned)h) << 16);
}

// ---- decompose weights + x into bf16 hi/lo planes (one launch, 6 segments) --
__global__ __launch_bounds__(256) void split_w6(
    const float* __restrict__ s0, const float* __restrict__ s1,
    const float* __restrict__ s2, const float* __restrict__ s3,
    const float* __restrict__ s4, const float* __restrict__ s5,
    ush* h0, ush* l0, ush* h1, ush* l1, ush* h2, ush* l2,
    ush* h3, ush* l3, ush* h4, ush* l4, ush* h5, ush* l5)
{
  const float* srcs[6] = {s0, s1, s2, s3, s4, s5};
  ush* hs[6] = {h0, h1, h2, h3, h4, h5};
  ush* ls[6] = {l0, l1, l2, l3, l4, l5};
  const int ns[6] = {1048576, 65536, 65536, 49152, 1048576, 2097152};
  int seg = blockIdx.y;
  int i = (blockIdx.x * 256 + threadIdx.x) * 4;
  if (i >= ns[seg]) return;
  float4 v = *(const float4*)(srcs[seg] + i);
  ushort4 hv, lv;
  hv.x = f2bf(v.x); lv.x = f2bf(v.x - bf2f(hv.x));
  hv.y = f2bf(v.y); lv.y = f2bf(v.y - bf2f(hv.y));
  hv.z = f2bf(v.z); lv.z = f2bf(v.z - bf2f(hv.z));
  hv.w = f2bf(v.w); lv.w = f2bf(v.w - bf2f(hv.w));
  *(ushort4*)(hs[seg] + i) = hv;
  *(ushort4*)(ls[seg] + i) = lv;
}

// ---- split-bf16 MFMA GEMM body: Y = A @ W^T, 64x64 tile, BK=32 --------------
// A either pre-split planes (Ah_/Al_) or f32 (Af, split inline during staging).
__device__ __forceinline__ void gemm64_body(
    const float* __restrict__ Af,
    const ush* __restrict__ Ah_, const ush* __restrict__ Al_,
    const ush* __restrict__ Wh, const ush* __restrict__ Wl,
    float* Yf, ush* Yh, ush* Yl, ush* YT, int N, int K, int m0, int n0,
    ush Ash[64][40], ush Asl[64][40], ush Bsh[64][40], ush Bsl[64][40])
{
  const int tid = threadIdx.x;
  const int wave = tid >> 6, lane = tid & 63;
  const int quad = lane >> 4, c16 = lane & 15;
  const int wm = wave >> 1, wn = wave & 1;
  const int ar = tid >> 2, ac = (tid & 3) * 8;
  f32x4 acc[2][2] = {};
  for (int k0 = 0; k0 < K; k0 += 32) {
    __syncthreads();
    if (Af) {                       // stage A from f32 with inline split
      const float* src = Af + (size_t)(m0 + ar) * K + k0 + ac;
      float4 u = *(const float4*)(src);
      float4 w2 = *(const float4*)(src + 4);
      float f[8] = {u.x, u.y, u.z, u.w, w2.x, w2.y, w2.z, w2.w};
      bf16x8 hv, lv;
      #pragma unroll
      for (int j = 0; j < 8; ++j) {
        ush hb = f2bf(f[j]);
        hv[j] = (short)hb;
        lv[j] = (short)f2bf(f[j] - bf2f(hb));
      }
      *(bf16x8*)&Ash[ar][ac] = hv;
      *(bf16x8*)&Asl[ar][ac] = lv;
    } else {                        // stage A from pre-split planes
      *(bf16x8*)&Ash[ar][ac] = *(const bf16x8*)(Ah_ + (size_t)(m0 + ar) * K + k0 + ac);
      *(bf16x8*)&Asl[ar][ac] = *(const bf16x8*)(Al_ + (size_t)(m0 + ar) * K + k0 + ac);
    }
    {
      bf16x8 bh = {}, bl = {};
      if (n0 + ar < N) {
        bh = *(const bf16x8*)(Wh + (size_t)(n0 + ar) * K + k0 + ac);
        bl = *(const bf16x8*)(Wl + (size_t)(n0 + ar) * K + k0 + ac);
      }
      *(bf16x8*)&Bsh[ar][ac] = bh;
      *(bf16x8*)&Bsl[ar][ac] = bl;
    }
    __syncthreads();
    bf16x8 Ah[2], Al[2], Bh[2], Bl[2];
    #pragma unroll
    for (int mt = 0; mt < 2; ++mt) {
      Ah[mt] = *(const bf16x8*)&Ash[wm*32 + mt*16 + c16][quad*8];
      Al[mt] = *(const bf16x8*)&Asl[wm*32 + mt*16 + c16][quad*8];
    }
    #pragma unroll
    for (int nt = 0; nt < 2; ++nt) {
      Bh[nt] = *(const bf16x8*)&Bsh[wn*32 + nt*16 + c16][quad*8];
      Bl[nt] = *(const bf16x8*)&Bsl[wn*32 + nt*16 + c16][quad*8];
    }
    #pragma unroll
    for (int mt = 0; mt < 2; ++mt)
      #pragma unroll
      for (int nt = 0; nt < 2; ++nt) {
        acc[mt][nt] = __builtin_amdgcn_mfma_f32_16x16x32_bf16(Ah[mt], Bh[nt], acc[mt][nt], 0, 0, 0);
        acc[mt][nt] = __builtin_amdgcn_mfma_f32_16x16x32_bf16(Ah[mt], Bl[nt], acc[mt][nt], 0, 0, 0);
        acc[mt][nt] = __builtin_amdgcn_mfma_f32_16x16x32_bf16(Al[mt], Bh[nt], acc[mt][nt], 0, 0, 0);
      }
  }
  #pragma unroll
  for (int mt = 0; mt < 2; ++mt)
    #pragma unroll
    for (int nt = 0; nt < 2; ++nt) {
      int n = n0 + wn*32 + nt*16 + c16;
      if (n < N) {
        #pragma unroll
        for (int r = 0; r < 4; ++r) {
          int m = m0 + wm*32 + mt*16 + quad*4 + r;
          float vvv = acc[mt][nt][r];
          if (Yf) Yf[(size_t)m*N + n] = vvv;
          ush hb = f2bf(vvv);
          if (Yh) {
            Yh[(size_t)m*N + n] = hb;
            if (Yl) Yl[(size_t)m*N + n] = f2bf(vvv - bf2f(hb));
          }
          if (YT) YT[(size_t)n*T_TOK + m] = hb;
        }
      }
    }
}

__global__ __launch_bounds__(256) void gemm_split(
    const ush* __restrict__ Ah, const ush* __restrict__ Al,
    const ush* __restrict__ Wh, const ush* __restrict__ Wl,
    float* Yf, ush* Yh, ush* Yl, int N, int K)
{
  __shared__ ush Ash[64][40], Asl[64][40], Bsh[64][40], Bsl[64][40];
  gemm64_body(nullptr, Ah, Al, Wh, Wl, Yf, Yh, Yl, nullptr, N, K,
              blockIdx.y*64, blockIdx.x*64, Ash, Asl, Bsh, Bsl);
}

// out-projection: A = f32 ocmp, inline split
__global__ __launch_bounds__(256) void gemm_out(
    const float* __restrict__ Af,
    const ush* __restrict__ Wh, const ush* __restrict__ Wl,
    float* Yf, int N, int K)
{
  __shared__ ush Ash[64][40], Asl[64][40], Bsh[64][40], Bsl[64][40];
  gemm64_body(Af, nullptr, nullptr, Wh, Wl, Yf, nullptr, nullptr, nullptr,
              N, K, blockIdx.y*64, blockIdx.x*64, Ash, Asl, Bsh, Bsl);
}

// fused k/v/g projections: blockIdx.x = segment. v also writes transposed hi.
__global__ __launch_bounds__(256) void gemm_kvg(
    const ush* __restrict__ xh, const ush* __restrict__ xl,
    const ush* __restrict__ Wkh, const ush* __restrict__ Wkl,
    const ush* __restrict__ Wvh, const ush* __restrict__ Wvl,
    const ush* __restrict__ Wgh, const ush* __restrict__ Wgl,
    float* kbuf, ush* kb, float* vbuf, ush* vbT, float* gpj, int K)
{
  __shared__ ush Ash[64][40], Asl[64][40], Bsh[64][40], Bsl[64][40];
  const int seg = blockIdx.x;
  const ush *wh, *wl; float* yf; ush* yh = nullptr; ush* yt = nullptr; int N;
  if (seg == 0)      { wh = Wkh; wl = Wkl; yf = kbuf; yh = kb; N = 64; }
  else if (seg == 1) { wh = Wvh; wl = Wvl; yf = vbuf; yt = vbT; N = 64; }
  else               { wh = Wgh; wl = Wgl; yf = gpj;  N = 48; }
  gemm64_body(nullptr, xh, xl, wh, wl, yf, yh, nullptr, yt, N, K,
              blockIdx.y*64, 0, Ash, Asl, Bsh, Bsl);
}

// ---- mean-pool k,v into centroids, emit split-bf16 (kc [c][d], vcT [d][c]) --
__global__ void pool_kv(const float* __restrict__ k, const float* __restrict__ v,
    ush* __restrict__ kch, ush* __restrict__ kcl,
    ush* __restrict__ vth, ush* __restrict__ vtl)
{
  int c = blockIdx.x, d = threadIdx.x;
  float sk = 0.f, sv = 0.f;
  for (int i = 0; i < BS; ++i) {
    sk += k[(size_t)(c*BS + i)*HD + d];
    sv += v[(size_t)(c*BS + i)*HD + d];
  }
  sk *= (1.f/BS); sv *= (1.f/BS);
  ush kh = f2bf(sk);
  kch[c*HD + d] = kh;
  kcl[c*HD + d] = f2bf(sk - bf2f(kh));
  ush vh = f2bf(sv);
  vth[d*NB + c] = vh;
  vtl[d*NB + c] = f2bf(sv - bf2f(vh));
}

// ---- compressed attention + top-k, MFMA, one wave per token (4 tokens/WG) ---
__global__ __launch_bounds__(256) void cmp_attn_mfma(
    const ush* __restrict__ qh, const ush* __restrict__ ql,
    const ush* __restrict__ kch, const ush* __restrict__ kcl,
    const ush* __restrict__ vth, const ush* __restrict__ vtl,
    float* __restrict__ ocmp, int* __restrict__ blkp)
{
  __shared__ float Pls[4][16][36];
  const int tid = threadIdx.x, w = tid >> 6, lane = tid & 63;
  const int quad = lane >> 4, c16 = lane & 15;
  const int t = blockIdx.x * 4 + w;

  const ush* qrh = qh + (size_t)t*DM + c16*HD + quad*8;
  const ush* qrl = ql + (size_t)t*DM + c16*HD + quad*8;
  bf16x8 qah0 = *(const bf16x8*)(qrh);
  bf16x8 qah1 = *(const bf16x8*)(qrh + 32);
  bf16x8 qal0 = *(const bf16x8*)(qrl);
  bf16x8 qal1 = *(const bf16x8*)(qrl + 32);

  f32x4 s[2];
  #pragma unroll
  for (int nh = 0; nh < 2; ++nh) {
    const int crow = nh*16 + c16;
    bf16x8 kh0 = *(const bf16x8*)(kch + crow*HD + quad*8);
    bf16x8 kh1 = *(const bf16x8*)(kch + crow*HD + 32 + quad*8);
    bf16x8 kl0 = *(const bf16x8*)(kcl + crow*HD + quad*8);
    bf16x8 kl1 = *(const bf16x8*)(kcl + crow*HD + 32 + quad*8);
    f32x4 acc = {0.f, 0.f, 0.f, 0.f};
    acc = __builtin_amdgcn_mfma_f32_16x16x32_bf16(qah0, kh0, acc, 0, 0, 0);
    acc = __builtin_amdgcn_mfma_f32_16x16x32_bf16(qah1, kh1, acc, 0, 0, 0);
    acc = __builtin_amdgcn_mfma_f32_16x16x32_bf16(qah0, kl0, acc, 0, 0, 0);
    acc = __builtin_amdgcn_mfma_f32_16x16x32_bf16(qah1, kl1, acc, 0, 0, 0);
    acc = __builtin_amdgcn_mfma_f32_16x16x32_bf16(qal0, kh0, acc, 0, 0, 0);
    acc = __builtin_amdgcn_mfma_f32_16x16x32_bf16(qal1, kh1, acc, 0, 0, 0);
    s[nh] = acc;
  }

  const int nvis = (t + 1) >> 6;
  const bool visA = (c16 < nvis), visB = (16 + c16 < nvis);
  float p[2][4];
  float iA = 0.f, iB = 0.f;
  #pragma unroll
  for (int r = 0; r < 4; ++r) {
    float sA = s[0][r] * 0.125f, sB = s[1][r] * 0.125f;
    float m = fmaxf(visA ? sA : -INFINITY, visB ? sB : -INFINITY);
    #pragma unroll
    for (int off = 1; off < 16; off <<= 1) m = fmaxf(m, __shfl_xor(m, off));
    float eA = visA ? __expf(sA - m) : 0.f;
    float eB = visB ? __expf(sB - m) : 0.f;
    float l = eA + eB;
    #pragma unroll
    for (int off = 1; off < 16; off <<= 1) l += __shfl_xor(l, off);
    float inv = (l > 0.f) ? 1.f / l : 0.f;
    p[0][r] = eA * inv; p[1][r] = eB * inv;
    iA += p[0][r]; iB += p[1][r];
  }
  iA += __shfl_xor(iA, 16); iA += __shfl_xor(iA, 32);
  iB += __shfl_xor(iB, 16); iB += __shfl_xor(iB, 32);

  #pragma unroll
  for (int nh = 0; nh < 2; ++nh)
    #pragma unroll
    for (int r = 0; r < 4; ++r)
      Pls[w][quad*4 + r][nh*16 + c16] = p[nh][r];

  {
    const int cur = t >> 6;
    float a;
    if (lane < 16) a = iA;
    else if (lane < 32) a = iB;
    else a = -INFINITY;
    if (lane < 32) {
      if (lane > cur) a = NEGF;
      if (lane == 0 || lane == cur) a = INFINITY;
    }
    for (int sidx = 0; sidx < S_SEL; ++sidx) {
      float bv = a; int bi = lane;
      #pragma unroll
      for (int off = 1; off < 64; off <<= 1) {
        float ov = __shfl_xor(bv, off); int oi = __shfl_xor(bi, off);
        if (ov > bv || (ov == bv && oi < bi)) { bv = ov; bi = oi; }
      }
      if (lane == 0) blkp[t*S_SEL + sidx] = bi;
      if (lane == bi) a = -INFINITY;
    }
  }
  __syncthreads();

  float4 pa = *(const float4*)&Pls[w][c16][quad*8];
  float4 pb = *(const float4*)&Pls[w][c16][quad*8 + 4];
  float pf[8] = {pa.x, pa.y, pa.z, pa.w, pb.x, pb.y, pb.z, pb.w};
  bf16x8 pah, pal;
  #pragma unroll
  for (int j = 0; j < 8; ++j) {
    ush hb = f2bf(pf[j]);
    pah[j] = (short)hb;
    pal[j] = (short)f2bf(pf[j] - bf2f(hb));
  }
  #pragma unroll
  for (int nb = 0; nb < 4; ++nb) {
    const int drow = nb*16 + c16;
    bf16x8 vh8 = *(const bf16x8*)(vth + drow*NB + quad*8);
    bf16x8 vl8 = *(const bf16x8*)(vtl + drow*NB + quad*8);
    f32x4 acc = {0.f, 0.f, 0.f, 0.f};
    acc = __builtin_amdgcn_mfma_f32_16x16x32_bf16(pah, vh8, acc, 0, 0, 0);
    acc = __builtin_amdgcn_mfma_f32_16x16x32_bf16(pah, vl8, acc, 0, 0, 0);
    acc = __builtin_amdgcn_mfma_f32_16x16x32_bf16(pal, vh8, acc, 0, 0, 0);
    #pragma unroll
    for (int r = 0; r < 4; ++r)
      ocmp[(size_t)t*DM + (quad*4 + r)*HD + nb*16 + c16] = acc[r];
  }
}

// ---- selected attention: ONE WAVE PER TOKEN, flash-style online softmax -----
// No __syncthreads: each wave owns its token; LDS transpose is wave-private
// (per-wave DS ops are in-order; compiler inserts lgkmcnt waits).
// Only min(cur+1,16) blocks processed: blocks > cur contribute exactly 0.
__global__ __launch_bounds__(256) void sel_attn_wave(
    const ush* __restrict__ qbh, const ush* __restrict__ kb,
    const ush* __restrict__ vbT, const float* __restrict__ gp,
    const int* __restrict__ blkp, float* __restrict__ ocmp_io)
{
  __shared__ ush Pt[4][16][72];                 // 9 KB, wave-private slices
  const int tid = threadIdx.x, w = tid >> 6, lane = tid & 63;
  const int quad = lane >> 4, c16 = lane & 15;
  const int t = blockIdx.x * 4 + w;
  const int cur = t >> 6;
  const int nblk = (cur + 1 < S_SEL) ? cur + 1 : S_SEL;

  const ush* qrow = qbh + (size_t)t*DM + c16*HD + quad*8;
  bf16x8 qa0 = *(const bf16x8*)(qrow);
  bf16x8 qa1 = *(const bf16x8*)(qrow + 32);

  f32x4 accO[4] = {};
  float m_run[4] = {-INFINITY, -INFINITY, -INFINITY, -INFINITY};
  float l_run[4] = {};

  for (int b = 0; b < nblk; ++b) {
    const int blk = blkp[t*S_SEL + b];          // wave-uniform scalar load
    const int base = blk * BS;
    // ---- QK^T: S[16 heads][64 toks] in 4 n-chunks ----
    f32x4 Sc[4];
    #pragma unroll
    for (int nc = 0; nc < 4; ++nc) {
      const ush* kp = kb + ((size_t)(base + nc*16 + c16)) * HD + quad*8;
      bf16x8 b0 = *(const bf16x8*)(kp);
      bf16x8 b1 = *(const bf16x8*)(kp + 32);
      f32x4 a = {0.f, 0.f, 0.f, 0.f};
      a = __builtin_amdgcn_mfma_f32_16x16x32_bf16(qa0, b0, a, 0, 0, 0);
      a = __builtin_amdgcn_mfma_f32_16x16x32_bf16(qa1, b1, a, 0, 0, 0);
      const bool ok = (base + nc*16 + c16) <= t;
      #pragma unroll
      for (int r = 0; r < 4; ++r) Sc[nc][r] = ok ? a[r]*0.125f : NEGF;
    }
    // ---- online softmax update (per head r; token dim = regs nc + 16 lanes) -
    float alpha[4], rs[4];
    #pragma unroll
    for (int r = 0; r < 4; ++r) {
      float mb = fmaxf(fmaxf(Sc[0][r], Sc[1][r]), fmaxf(Sc[2][r], Sc[3][r]));
      #pragma unroll
      for (int off = 1; off < 16; off <<= 1) mb = fmaxf(mb, __shfl_xor(mb, off));
      float mn = fmaxf(m_run[r], mb);
      alpha[r] = __expf(m_run[r] - mn);         // exp(-inf)=0 on first block
      m_run[r] = mn;
      rs[r] = 0.f;
    }
    #pragma unroll
    for (int nc = 0; nc < 4; ++nc)
      #pragma unroll
      for (int r = 0; r < 4; ++r) {
        ush pb = f2bf(__expf(Sc[nc][r] - m_run[r]));
        Pt[w][quad*4 + r][nc*16 + c16] = pb;
        rs[r] += bf2f(pb);
      }
    #pragma unroll
    for (int r = 0; r < 4; ++r) {
      #pragma unroll
      for (int off = 1; off < 16; off <<= 1) rs[r] += __shfl_xor(rs[r], off);
      l_run[r] = l_run[r]*alpha[r] + rs[r];
    }
    #pragma unroll
    for (int dn = 0; dn < 4; ++dn)
      #pragma unroll
      for (int r = 0; r < 4; ++r) accO[dn][r] *= alpha[r];
    // ---- P (A-layout via wave-private LDS transpose) @ V ----
    bf16x8 pa0 = *(const bf16x8*)&Pt[w][c16][quad*8];
    bf16x8 pa1 = *(const bf16x8*)&Pt[w][c16][32 + quad*8];
    #pragma unroll
    for (int dn = 0; dn < 4; ++dn) {
      const ush* vp = vbT + (size_t)(dn*16 + c16) * T_TOK + base + quad*8;
      bf16x8 v0 = *(const bf16x8*)(vp);
      bf16x8 v1 = *(const bf16x8*)(vp + 32);
      accO[dn] = __builtin_amdgcn_mfma_f32_16x16x32_bf16(pa0, v0, accO[dn], 0, 0, 0);
      accO[dn] = __builtin_amdgcn_mfma_f32_16x16x32_bf16(pa1, v1, accO[dn], 0, 0, 0);
    }
  }

  // ---- epilogue: gates + combine with o_cmp (f32, in place) ----
  #pragma unroll
  for (int r = 0; r < 4; ++r) {
    const int h = quad*4 + r;
    float ga = gp[(size_t)t*48 + h*3 + 0];
    float gb = gp[(size_t)t*48 + h*3 + 1];
    float gcv = 1.f/(1.f + __expf(-ga));
    float gsv = 1.f/(1.f + __expf(-gb));
    float inv = gsv / l_run[r];
    #pragma unroll
    for (int dn = 0; dn < 4; ++dn) {
      size_t idx = (size_t)t*DM + h*HD + dn*16 + c16;
      ocmp_io[idx] = accO[dn][r]*inv + ocmp_io[idx]*gcv;
    }
  }
}

extern "C" void kernel_launch(void* const* d_in, const int* in_sizes, int n_in,
                              void* d_out, int out_size, void* d_ws, size_t ws_size,
                              hipStream_t stream)
{
  const float* x  = (const float*)d_in[0];
  const float* Wq = (const float*)d_in[1];
  const float* Wk = (const float*)d_in[2];
  const float* Wv = (const float*)d_in[3];
  const float* Wg = (const float*)d_in[4];
  const float* Wo = (const float*)d_in[5];
  float* out = (float*)d_out;

  float* ws   = (float*)d_ws;
  float* kbuf = ws;                                // 2048*64 f32
  float* vbuf = kbuf + (size_t)T_TOK*HD;
  float* gpj  = vbuf + (size_t)T_TOK*HD;           // 2048*48 f32
  float* ocmp = gpj  + (size_t)T_TOK*48;           // 2048*1024 f32
  int*   blkp = (int*)(ocmp + (size_t)T_TOK*DM);   // 2048*16
  ush* xh  = (ush*)(blkp + T_TOK*S_SEL);           // 2048*1024
  ush* xl  = xh + (size_t)T_TOK*DM;
  ush* qbh = xl + (size_t)T_TOK*DM;
  ush* qbl = qbh + (size_t)T_TOK*DM;
  ush* kb  = qbl + (size_t)T_TOK*DM;               // 2048*64
  ush* vbT = kb  + (size_t)T_TOK*HD;               // 64*2048 (transposed)
  ush* kch = vbT + (size_t)T_TOK*HD;
  ush* kcl = kch + NB*HD;
  ush* vth = kcl + NB*HD;
  ush* vtl = vth + NB*HD;
  ush* Wqh = vtl + NB*HD;
  ush* Wql = Wqh + 1048576;
  ush* Wkh = Wql + 1048576;
  ush* Wkl = Wkh + 65536;
  ush* Wvh = Wkl + 65536;
  ush* Wvl = Wvh + 65536;
  ush* Wgh = Wvl + 65536;
  ush* Wgl = Wgh + 49152;
  ush* Woh = Wgl + 49152;
  ush* Wol = Woh + 1048576;

  split_w6<<<dim3(2048, 6), 256, 0, stream>>>(Wq, Wk, Wv, Wg, Wo, x,
      Wqh, Wql, Wkh, Wkl, Wvh, Wvl, Wgh, Wgl, Woh, Wol, xh, xl);
  gemm_split<<<dim3(16, 32), 256, 0, stream>>>(xh, xl, Wqh, Wql,
      nullptr, qbh, qbl, DM, DM);
  gemm_kvg<<<dim3(3, 32), 256, 0, stream>>>(xh, xl, Wkh, Wkl, Wvh, Wvl,
      Wgh, Wgl, kbuf, kb, vbuf, vbT, gpj, DM);
  pool_kv<<<NB, HD, 0, stream>>>(kbuf, vbuf, kch, kcl, vth, vtl);
  cmp_attn_mfma<<<T_TOK/4, 256, 0, stream>>>(qbh, qbl, kch, kcl, vth, vtl,
      ocmp, blkp);
  sel_attn_wave<<<T_TOK/4, 256, 0, stream>>>(qbh, kb, vbT, gpj, blkp, ocmp);
  gemm_out<<<dim3(16, 32), 256, 0, stream>>>(ocmp, Woh, Wol, out, DM, DM);
}

// Round 7
// 219.993 us; speedup vs baseline: 1.3363x; 1.1362x over previous
//
#include <hip/hip_runtime.h>
#include <math.h>

#define T_TOK 2048
#define DM 1024
#define HQ 16
#define HD 64
#define NB 32
#define BS 64
#define S_SEL 16
#define NEGF (-1e30f)

typedef __attribute__((ext_vector_type(8))) short bf16x8;
typedef __attribute__((ext_vector_type(4))) float f32x4;
typedef unsigned short ush;

__device__ __forceinline__ ush f2bf(float x) {
  unsigned u = __float_as_uint(x);
  return (ush)((u + 0x7fffu + ((u >> 16) & 1u)) >> 16);
}
__device__ __forceinline__ float bf2f(ush h) {
  return __uint_as_float(((unsigned)h) << 16);
}

// ---- decompose weights + x into bf16 hi/lo planes (one launch, 6 segments) --
__global__ __launch_bounds__(256) void split_w6(
    const float* __restrict__ s0, const float* __restrict__ s1,
    const float* __restrict__ s2, const float* __restrict__ s3,
    const float* __restrict__ s4, const float* __restrict__ s5,
    ush* h0, ush* l0, ush* h1, ush* l1, ush* h2, ush* l2,
    ush* h3, ush* l3, ush* h4, ush* l4, ush* h5, ush* l5)
{
  const float* srcs[6] = {s0, s1, s2, s3, s4, s5};
  ush* hs[6] = {h0, h1, h2, h3, h4, h5};
  ush* ls[6] = {l0, l1, l2, l3, l4, l5};
  const int ns[6] = {1048576, 65536, 65536, 49152, 1048576, 2097152};
  int seg = blockIdx.y;
  int i = (blockIdx.x * 256 + threadIdx.x) * 4;
  if (i >= ns[seg]) return;
  float4 v = *(const float4*)(srcs[seg] + i);
  ushort4 hv, lv;
  hv.x = f2bf(v.x); lv.x = f2bf(v.x - bf2f(hv.x));
  hv.y = f2bf(v.y); lv.y = f2bf(v.y - bf2f(hv.y));
  hv.z = f2bf(v.z); lv.z = f2bf(v.z - bf2f(hv.z));
  hv.w = f2bf(v.w); lv.w = f2bf(v.w - bf2f(hv.w));
  *(ushort4*)(hs[seg] + i) = hv;
  *(ushort4*)(ls[seg] + i) = lv;
}

// ---- split-bf16 MFMA GEMM body: Y = A @ W^T, 64x64 tile, BK=32 --------------
__device__ __forceinline__ void gemm64_body(
    const float* __restrict__ Af,
    const ush* __restrict__ Ah_, const ush* __restrict__ Al_,
    const ush* __restrict__ Wh, const ush* __restrict__ Wl,
    float* Yf, ush* Yh, ush* Yl, ush* YT, int N, int K, int m0, int n0,
    ush Ash[64][40], ush Asl[64][40], ush Bsh[64][40], ush Bsl[64][40])
{
  const int tid = threadIdx.x;
  const int wave = tid >> 6, lane = tid & 63;
  const int quad = lane >> 4, c16 = lane & 15;
  const int wm = wave >> 1, wn = wave & 1;
  const int ar = tid >> 2, ac = (tid & 3) * 8;
  f32x4 acc[2][2] = {};
  for (int k0 = 0; k0 < K; k0 += 32) {
    __syncthreads();
    if (Af) {
      const float* src = Af + (size_t)(m0 + ar) * K + k0 + ac;
      float4 u = *(const float4*)(src);
      float4 w2 = *(const float4*)(src + 4);
      float f[8] = {u.x, u.y, u.z, u.w, w2.x, w2.y, w2.z, w2.w};
      bf16x8 hv, lv;
      #pragma unroll
      for (int j = 0; j < 8; ++j) {
        ush hb = f2bf(f[j]);
        hv[j] = (short)hb;
        lv[j] = (short)f2bf(f[j] - bf2f(hb));
      }
      *(bf16x8*)&Ash[ar][ac] = hv;
      *(bf16x8*)&Asl[ar][ac] = lv;
    } else {
      *(bf16x8*)&Ash[ar][ac] = *(const bf16x8*)(Ah_ + (size_t)(m0 + ar) * K + k0 + ac);
      *(bf16x8*)&Asl[ar][ac] = *(const bf16x8*)(Al_ + (size_t)(m0 + ar) * K + k0 + ac);
    }
    {
      bf16x8 bh = {}, bl = {};
      if (n0 + ar < N) {
        bh = *(const bf16x8*)(Wh + (size_t)(n0 + ar) * K + k0 + ac);
        bl = *(const bf16x8*)(Wl + (size_t)(n0 + ar) * K + k0 + ac);
      }
      *(bf16x8*)&Bsh[ar][ac] = bh;
      *(bf16x8*)&Bsl[ar][ac] = bl;
    }
    __syncthreads();
    bf16x8 Ah[2], Al[2], Bh[2], Bl[2];
    #pragma unroll
    for (int mt = 0; mt < 2; ++mt) {
      Ah[mt] = *(const bf16x8*)&Ash[wm*32 + mt*16 + c16][quad*8];
      Al[mt] = *(const bf16x8*)&Asl[wm*32 + mt*16 + c16][quad*8];
    }
    #pragma unroll
    for (int nt = 0; nt < 2; ++nt) {
      Bh[nt] = *(const bf16x8*)&Bsh[wn*32 + nt*16 + c16][quad*8];
      Bl[nt] = *(const bf16x8*)&Bsl[wn*32 + nt*16 + c16][quad*8];
    }
    #pragma unroll
    for (int mt = 0; mt < 2; ++mt)
      #pragma unroll
      for (int nt = 0; nt < 2; ++nt) {
        acc[mt][nt] = __builtin_amdgcn_mfma_f32_16x16x32_bf16(Ah[mt], Bh[nt], acc[mt][nt], 0, 0, 0);
        acc[mt][nt] = __builtin_amdgcn_mfma_f32_16x16x32_bf16(Ah[mt], Bl[nt], acc[mt][nt], 0, 0, 0);
        acc[mt][nt] = __builtin_amdgcn_mfma_f32_16x16x32_bf16(Al[mt], Bh[nt], acc[mt][nt], 0, 0, 0);
      }
  }
  #pragma unroll
  for (int mt = 0; mt < 2; ++mt)
    #pragma unroll
    for (int nt = 0; nt < 2; ++nt) {
      int n = n0 + wn*32 + nt*16 + c16;
      if (n < N) {
        #pragma unroll
        for (int r = 0; r < 4; ++r) {
          int m = m0 + wm*32 + mt*16 + quad*4 + r;
          float vvv = acc[mt][nt][r];
          if (Yf) Yf[(size_t)m*N + n] = vvv;
          ush hb = f2bf(vvv);
          if (Yh) {
            Yh[(size_t)m*N + n] = hb;
            if (Yl) Yl[(size_t)m*N + n] = f2bf(vvv - bf2f(hb));
          }
          if (YT) YT[(size_t)n*T_TOK + m] = hb;
        }
      }
    }
}

// fused q + k/v/g projections in ONE dispatch: x: 0-15 = q n-tiles, 16-18 = kvg
__global__ __launch_bounds__(256) void gemm_proj(
    const ush* __restrict__ xh, const ush* __restrict__ xl,
    const ush* __restrict__ Wqh, const ush* __restrict__ Wql,
    const ush* __restrict__ Wkh, const ush* __restrict__ Wkl,
    const ush* __restrict__ Wvh, const ush* __restrict__ Wvl,
    const ush* __restrict__ Wgh, const ush* __restrict__ Wgl,
    ush* qbh, ush* qbl,
    float* kbuf, ush* kb, float* vbuf, ush* vbT, float* gpj, int K)
{
  __shared__ ush Ash[64][40], Asl[64][40], Bsh[64][40], Bsl[64][40];
  const int bx = blockIdx.x;
  if (bx < 16) {
    gemm64_body(nullptr, xh, xl, Wqh, Wql, nullptr, qbh, qbl, nullptr,
                DM, K, blockIdx.y*64, bx*64, Ash, Asl, Bsh, Bsl);
  } else {
    const int seg = bx - 16;
    const ush *wh, *wl; float* yf; ush* yh = nullptr; ush* yt = nullptr; int N;
    if (seg == 0)      { wh = Wkh; wl = Wkl; yf = kbuf; yh = kb; N = 64; }
    else if (seg == 1) { wh = Wvh; wl = Wvl; yf = vbuf; yt = vbT; N = 64; }
    else               { wh = Wgh; wl = Wgl; yf = gpj;  N = 48; }
    gemm64_body(nullptr, xh, xl, wh, wl, yf, yh, nullptr, yt, N, K,
                blockIdx.y*64, 0, Ash, Asl, Bsh, Bsl);
  }
}

// out-projection: A = f32 ocmp, inline split
__global__ __launch_bounds__(256) void gemm_out(
    const float* __restrict__ Af,
    const ush* __restrict__ Wh, const ush* __restrict__ Wl,
    float* Yf, int N, int K)
{
  __shared__ ush Ash[64][40], Asl[64][40], Bsh[64][40], Bsl[64][40];
  gemm64_body(Af, nullptr, nullptr, Wh, Wl, Yf, nullptr, nullptr, nullptr,
              N, K, blockIdx.y*64, blockIdx.x*64, Ash, Asl, Bsh, Bsl);
}

// ---- mean-pool k,v into centroids, emit split-bf16 (kc [c][d], vcT [d][c]) --
__global__ void pool_kv(const float* __restrict__ k, const float* __restrict__ v,
    ush* __restrict__ kch, ush* __restrict__ kcl,
    ush* __restrict__ vth, ush* __restrict__ vtl)
{
  int c = blockIdx.x, d = threadIdx.x;
  float sk = 0.f, sv = 0.f;
  for (int i = 0; i < BS; ++i) {
    sk += k[(size_t)(c*BS + i)*HD + d];
    sv += v[(size_t)(c*BS + i)*HD + d];
  }
  sk *= (1.f/BS); sv *= (1.f/BS);
  ush kh = f2bf(sk);
  kch[c*HD + d] = kh;
  kcl[c*HD + d] = f2bf(sk - bf2f(kh));
  ush vh = f2bf(sv);
  vth[d*NB + c] = vh;
  vtl[d*NB + c] = f2bf(sv - bf2f(vh));
}

// ---- compressed attention + top-k, MFMA, one wave per token (4 tokens/WG) ---
__global__ __launch_bounds__(256) void cmp_attn_mfma(
    const ush* __restrict__ qh, const ush* __restrict__ ql,
    const ush* __restrict__ kch, const ush* __restrict__ kcl,
    const ush* __restrict__ vth, const ush* __restrict__ vtl,
    float* __restrict__ ocmp, int* __restrict__ blkp)
{
  __shared__ float Pls[4][16][36];
  const int tid = threadIdx.x, w = tid >> 6, lane = tid & 63;
  const int quad = lane >> 4, c16 = lane & 15;
  const int t = blockIdx.x * 4 + w;

  const ush* qrh = qh + (size_t)t*DM + c16*HD + quad*8;
  const ush* qrl = ql + (size_t)t*DM + c16*HD + quad*8;
  bf16x8 qah0 = *(const bf16x8*)(qrh);
  bf16x8 qah1 = *(const bf16x8*)(qrh + 32);
  bf16x8 qal0 = *(const bf16x8*)(qrl);
  bf16x8 qal1 = *(const bf16x8*)(qrl + 32);

  f32x4 s[2];
  #pragma unroll
  for (int nh = 0; nh < 2; ++nh) {
    const int crow = nh*16 + c16;
    bf16x8 kh0 = *(const bf16x8*)(kch + crow*HD + quad*8);
    bf16x8 kh1 = *(const bf16x8*)(kch + crow*HD + 32 + quad*8);
    bf16x8 kl0 = *(const bf16x8*)(kcl + crow*HD + quad*8);
    bf16x8 kl1 = *(const bf16x8*)(kcl + crow*HD + 32 + quad*8);
    f32x4 acc = {0.f, 0.f, 0.f, 0.f};
    acc = __builtin_amdgcn_mfma_f32_16x16x32_bf16(qah0, kh0, acc, 0, 0, 0);
    acc = __builtin_amdgcn_mfma_f32_16x16x32_bf16(qah1, kh1, acc, 0, 0, 0);
    acc = __builtin_amdgcn_mfma_f32_16x16x32_bf16(qah0, kl0, acc, 0, 0, 0);
    acc = __builtin_amdgcn_mfma_f32_16x16x32_bf16(qah1, kl1, acc, 0, 0, 0);
    acc = __builtin_amdgcn_mfma_f32_16x16x32_bf16(qal0, kh0, acc, 0, 0, 0);
    acc = __builtin_amdgcn_mfma_f32_16x16x32_bf16(qal1, kh1, acc, 0, 0, 0);
    s[nh] = acc;
  }

  const int nvis = (t + 1) >> 6;
  const bool visA = (c16 < nvis), visB = (16 + c16 < nvis);
  float p[2][4];
  float iA = 0.f, iB = 0.f;
  #pragma unroll
  for (int r = 0; r < 4; ++r) {
    float sA = s[0][r] * 0.125f, sB = s[1][r] * 0.125f;
    float m = fmaxf(visA ? sA : -INFINITY, visB ? sB : -INFINITY);
    #pragma unroll
    for (int off = 1; off < 16; off <<= 1) m = fmaxf(m, __shfl_xor(m, off));
    float eA = visA ? __expf(sA - m) : 0.f;
    float eB = visB ? __expf(sB - m) : 0.f;
    float l = eA + eB;
    #pragma unroll
    for (int off = 1; off < 16; off <<= 1) l += __shfl_xor(l, off);
    float inv = (l > 0.f) ? 1.f / l : 0.f;
    p[0][r] = eA * inv; p[1][r] = eB * inv;
    iA += p[0][r]; iB += p[1][r];
  }
  iA += __shfl_xor(iA, 16); iA += __shfl_xor(iA, 32);
  iB += __shfl_xor(iB, 16); iB += __shfl_xor(iB, 32);

  #pragma unroll
  for (int nh = 0; nh < 2; ++nh)
    #pragma unroll
    for (int r = 0; r < 4; ++r)
      Pls[w][quad*4 + r][nh*16 + c16] = p[nh][r];

  {
    const int cur = t >> 6;
    float a;
    if (lane < 16) a = iA;
    else if (lane < 32) a = iB;
    else a = -INFINITY;
    if (lane < 32) {
      if (lane > cur) a = NEGF;
      if (lane == 0 || lane == cur) a = INFINITY;
    }
    for (int sidx = 0; sidx < S_SEL; ++sidx) {
      float bv = a; int bi = lane;
      #pragma unroll
      for (int off = 1; off < 64; off <<= 1) {
        float ov = __shfl_xor(bv, off); int oi = __shfl_xor(bi, off);
        if (ov > bv || (ov == bv && oi < bi)) { bv = ov; bi = oi; }
      }
      if (lane == 0) blkp[t*S_SEL + sidx] = bi;
      if (lane == bi) a = -INFINITY;
    }
  }
  __syncthreads();

  float4 pa = *(const float4*)&Pls[w][c16][quad*8];
  float4 pb = *(const float4*)&Pls[w][c16][quad*8 + 4];
  float pf[8] = {pa.x, pa.y, pa.z, pa.w, pb.x, pb.y, pb.z, pb.w};
  bf16x8 pah, pal;
  #pragma unroll
  for (int j = 0; j < 8; ++j) {
    ush hb = f2bf(pf[j]);
    pah[j] = (short)hb;
    pal[j] = (short)f2bf(pf[j] - bf2f(hb));
  }
  #pragma unroll
  for (int nb = 0; nb < 4; ++nb) {
    const int drow = nb*16 + c16;
    bf16x8 vh8 = *(const bf16x8*)(vth + drow*NB + quad*8);
    bf16x8 vl8 = *(const bf16x8*)(vtl + drow*NB + quad*8);
    f32x4 acc = {0.f, 0.f, 0.f, 0.f};
    acc = __builtin_amdgcn_mfma_f32_16x16x32_bf16(pah, vh8, acc, 0, 0, 0);
    acc = __builtin_amdgcn_mfma_f32_16x16x32_bf16(pah, vl8, acc, 0, 0, 0);
    acc = __builtin_amdgcn_mfma_f32_16x16x32_bf16(pal, vh8, acc, 0, 0, 0);
    #pragma unroll
    for (int r = 0; r < 4; ++r)
      ocmp[(size_t)t*DM + (quad*4 + r)*HD + nb*16 + c16] = acc[r];
  }
}

// ---- selected attention: ONE WG PER TOKEN, 4 waves split the blocks ---------
// Wave w owns blocks {w, w+4, w+8, w+12} with private online softmax;
// flash combine across waves via LDS. Blocks > cur skipped (contribute 0).
__global__ __launch_bounds__(256) void sel_attn_ws(
    const ush* __restrict__ qbh, const ush* __restrict__ kb,
    const ush* __restrict__ vbT, const float* __restrict__ gp,
    const int* __restrict__ blkp, float* __restrict__ ocmp_io)
{
  // union: Pt (bf16 P transpose, wave-private) / cO (f32 combine buffer)
  __shared__ char smem[4 * 16 * 68 * 4];        // 17.4 KB
  ush  (*Pt)[16][72] = (ush (*)[16][72])smem;   // 9.2 KB in-loop
  float (*cO)[16][68] = (float (*)[16][68])smem;
  __shared__ float cM[4][16], cL[4][16];

  const int tid = threadIdx.x, w = tid >> 6, lane = tid & 63;
  const int quad = lane >> 4, c16 = lane & 15;
  const int t = blockIdx.x;
  const int cur = t >> 6;
  const int nblk = (cur + 1 < S_SEL) ? cur + 1 : S_SEL;

  const ush* qrow = qbh + (size_t)t*DM + c16*HD + quad*8;
  bf16x8 qa0 = *(const bf16x8*)(qrow);
  bf16x8 qa1 = *(const bf16x8*)(qrow + 32);

  f32x4 accO[4] = {};
  float m_run[4] = {-INFINITY, -INFINITY, -INFINITY, -INFINITY};
  float l_run[4] = {};

  for (int b = w; b < nblk; b += 4) {
    const int blk = blkp[t*S_SEL + b];
    const int base = blk * BS;
    f32x4 Sc[4];
    #pragma unroll
    for (int nc = 0; nc < 4; ++nc) {
      const ush* kp = kb + ((size_t)(base + nc*16 + c16)) * HD + quad*8;
      bf16x8 b0 = *(const bf16x8*)(kp);
      bf16x8 b1 = *(const bf16x8*)(kp + 32);
      f32x4 a = {0.f, 0.f, 0.f, 0.f};
      a = __builtin_amdgcn_mfma_f32_16x16x32_bf16(qa0, b0, a, 0, 0, 0);
      a = __builtin_amdgcn_mfma_f32_16x16x32_bf16(qa1, b1, a, 0, 0, 0);
      const bool ok = (base + nc*16 + c16) <= t;
      #pragma unroll
      for (int r = 0; r < 4; ++r) Sc[nc][r] = ok ? a[r]*0.125f : NEGF;
    }
    float alpha[4], rs[4];
    #pragma unroll
    for (int r = 0; r < 4; ++r) {
      float mb = fmaxf(fmaxf(Sc[0][r], Sc[1][r]), fmaxf(Sc[2][r], Sc[3][r]));
      #pragma unroll
      for (int off = 1; off < 16; off <<= 1) mb = fmaxf(mb, __shfl_xor(mb, off));
      float mn = fmaxf(m_run[r], mb);
      alpha[r] = __expf(m_run[r] - mn);
      m_run[r] = mn;
      rs[r] = 0.f;
    }
    #pragma unroll
    for (int nc = 0; nc < 4; ++nc)
      #pragma unroll
      for (int r = 0; r < 4; ++r) {
        ush pb = f2bf(__expf(Sc[nc][r] - m_run[r]));
        Pt[w][quad*4 + r][nc*16 + c16] = pb;
        rs[r] += bf2f(pb);
      }
    #pragma unroll
    for (int r = 0; r < 4; ++r) {
      #pragma unroll
      for (int off = 1; off < 16; off <<= 1) rs[r] += __shfl_xor(rs[r], off);
      l_run[r] = l_run[r]*alpha[r] + rs[r];
    }
    #pragma unroll
    for (int dn = 0; dn < 4; ++dn)
      #pragma unroll
      for (int r = 0; r < 4; ++r) accO[dn][r] *= alpha[r];
    bf16x8 pa0 = *(const bf16x8*)&Pt[w][c16][quad*8];
    bf16x8 pa1 = *(const bf16x8*)&Pt[w][c16][32 + quad*8];
    #pragma unroll
    for (int dn = 0; dn < 4; ++dn) {
      const ush* vp = vbT + (size_t)(dn*16 + c16) * T_TOK + base + quad*8;
      bf16x8 v0 = *(const bf16x8*)(vp);
      bf16x8 v1 = *(const bf16x8*)(vp + 32);
      accO[dn] = __builtin_amdgcn_mfma_f32_16x16x32_bf16(pa0, v0, accO[dn], 0, 0, 0);
      accO[dn] = __builtin_amdgcn_mfma_f32_16x16x32_bf16(pa1, v1, accO[dn], 0, 0, 0);
    }
  }

  // ---- flash combine across waves ----
  __syncthreads();                              // all Pt reads done
  if (c16 == 0) {
    #pragma unroll
    for (int r = 0; r < 4; ++r) {
      cM[w][quad*4 + r] = m_run[r];
      cL[w][quad*4 + r] = l_run[r];
    }
  }
  #pragma unroll
  for (int dn = 0; dn < 4; ++dn)
    #pragma unroll
    for (int r = 0; r < 4; ++r)
      cO[w][quad*4 + r][dn*16 + c16] = accO[dn][r];
  __syncthreads();

  // wave w finalizes d-chunk w: d = w*16 + c16, heads h = quad*4 + r
  #pragma unroll
  for (int r = 0; r < 4; ++r) {
    const int h = quad*4 + r;
    float M = fmaxf(fmaxf(cM[0][h], cM[1][h]), fmaxf(cM[2][h], cM[3][h]));
    float L = 0.f, O = 0.f;
    #pragma unroll
    for (int wv = 0; wv < 4; ++wv) {
      float sc = __expf(cM[wv][h] - M);
      L += sc * cL[wv][h];
      O += sc * cO[wv][h][w*16 + c16];
    }
    float ga = gp[(size_t)t*48 + h*3 + 0];
    float gb = gp[(size_t)t*48 + h*3 + 1];
    float gcv = 1.f/(1.f + __expf(-ga));
    float gsv = 1.f/(1.f + __expf(-gb));
    size_t idx = (size_t)t*DM + h*HD + w*16 + c16;
    ocmp_io[idx] = O * gsv / L + ocmp_io[idx] * gcv;
  }
}

extern "C" void kernel_launch(void* const* d_in, const int* in_sizes, int n_in,
                              void* d_out, int out_size, void* d_ws, size_t ws_size,
                              hipStream_t stream)
{
  const float* x  = (const float*)d_in[0];
  const float* Wq = (const float*)d_in[1];
  const float* Wk = (const float*)d_in[2];
  const float* Wv = (const float*)d_in[3];
  const float* Wg = (const float*)d_in[4];
  const float* Wo = (const float*)d_in[5];
  float* out = (float*)d_out;

  float* ws   = (float*)d_ws;
  float* kbuf = ws;                                // 2048*64 f32
  float* vbuf = kbuf + (size_t)T_TOK*HD;
  float* gpj  = vbuf + (size_t)T_TOK*HD;           // 2048*48 f32
  float* ocmp = gpj  + (size_t)T_TOK*48;           // 2048*1024 f32
  int*   blkp = (int*)(ocmp + (size_t)T_TOK*DM);   // 2048*16
  ush* xh  = (ush*)(blkp + T_TOK*S_SEL);           // 2048*1024
  ush* xl  = xh + (size_t)T_TOK*DM;
  ush* qbh = xl + (size_t)T_TOK*DM;
  ush* qbl = qbh + (size_t)T_TOK*DM;
  ush* kb  = qbl + (size_t)T_TOK*DM;               // 2048*64
  ush* vbT = kb  + (size_t)T_TOK*HD;               // 64*2048 (transposed)
  ush* kch = vbT + (size_t)T_TOK*HD;
  ush* kcl = kch + NB*HD;
  ush* vth = kcl + NB*HD;
  ush* vtl = vth + NB*HD;
  ush* Wqh = vtl + NB*HD;
  ush* Wql = Wqh + 1048576;
  ush* Wkh = Wql + 1048576;
  ush* Wkl = Wkh + 65536;
  ush* Wvh = Wkl + 65536;
  ush* Wvl = Wvh + 65536;
  ush* Wgh = Wvl + 65536;
  ush* Wgl = Wgh + 49152;
  ush* Woh = Wgl + 49152;
  ush* Wol = Woh + 1048576;

  split_w6<<<dim3(2048, 6), 256, 0, stream>>>(Wq, Wk, Wv, Wg, Wo, x,
      Wqh, Wql, Wkh, Wkl, Wvh, Wvl, Wgh, Wgl, Woh, Wol, xh, xl);
  gemm_proj<<<dim3(19, 32), 256, 0, stream>>>(xh, xl, Wqh, Wql,
      Wkh, Wkl, Wvh, Wvl, Wgh, Wgl, qbh, qbl, kbuf, kb, vbuf, vbT, gpj, DM);
  pool_kv<<<NB, HD, 0, stream>>>(kbuf, vbuf, kch, kcl, vth, vtl);
  cmp_attn_mfma<<<T_TOK/4, 256, 0, stream>>>(qbh, qbl, kch, kcl, vth, vtl,
      ocmp, blkp);
  sel_attn_ws<<<T_TOK, 256, 0, stream>>>(qbh, kb, vbT, gpj, blkp, ocmp);
  gemm_out<<<dim3(16, 32), 256, 0, stream>>>(ocmp, Woh, Wol, out, DM, DM);
}